// Round 10
// baseline (99.670 us; speedup 1.0000x reference)
//
#include <hip/hip_runtime.h>
#include <hip/hip_bf16.h>
#include <math.h>

// Differential attention, bf16 MFMA pipeline, split-KV flash attention with
// swapped-operand 32x32x16 MFMA softmax (T12). R10: XCD-aware block swizzle
// (attn 1D grid + gemm chunked remap) and RoPE fused into gemm1 epilogue
// (shfl_xor(·,1) pair exchange; rope pass eliminated, ropetv -> transv only).
// ws layout (bytes):
//   [0,4M)    xb      x as bf16             2048x1024
//   [4M,10M)  w1      [Wq;Wk;Wv] bf16       3072x1024
//   [10M,12M) wob     Wo bf16               1024x1024
//   [12M,24M) qkv     bf16, row stride 3072 (q|k|v); rope already applied to q,k
//   [24M,28M) vt      v transposed bf16     1024x2048  vt[d][s]
//   [28M,32M) atn     normalized wv bf16    2048x1024
//   [32M,+256K) cos/sin tables fp32         2048x16 each
//   [33M,+37.75M)  pOh  fp16 partial O  [2304 pids][2 subs][64 q][64 d]
//   [33M+37.75M,+2.36M) pML fp32 partial m,l [2304][2][2][64]
// pid = h*144 + qoff4(qt) + chunk;  chunk = 256 kv rows (4 k-tiles of 64)

typedef __bf16 bf16x8 __attribute__((ext_vector_type(8)));
typedef float f32x4 __attribute__((ext_vector_type(4)));
typedef float f32x16 __attribute__((ext_vector_type(16)));

#define LOG2E 1.4426950408889634f
#define SCALE 0.17677669529663687f /* 1/sqrt(32) */
#define C1EXP 0.25506100319239545f /* SCALE*LOG2E : exp2 scale for raw S */
#define DMAX_THR 31.36f            /* 8 / C1EXP : defer-max threshold, raw-S units */
#define LAM_INIT 0.783605766532f
#define ONE_M_LI 0.216394233468f

// async global->LDS, 16B per lane; lds base must be wave-uniform (lane scatters +l*16)
#define GLOAD16(g, l)                                                              \
  __builtin_amdgcn_global_load_lds((const __attribute__((address_space(1))) void*)(g), \
                                   (__attribute__((address_space(3))) void*)(l), 16, 0, 0)

__device__ __forceinline__ ushort f2b(float f) {
  unsigned u = __builtin_bit_cast(unsigned, f);
  u += 0x7fffu + ((u >> 16) & 1u);
  return (ushort)(u >> 16);
}
__device__ __forceinline__ float b2f(ushort h) {
  return __builtin_bit_cast(float, ((unsigned)h) << 16);
}
__device__ __forceinline__ ushort f2h(float f) {
  _Float16 h = (_Float16)f;
  return __builtin_bit_cast(ushort, h);
}
__device__ __forceinline__ float h2f(ushort u) {
  return (float)__builtin_bit_cast(_Float16, u);
}
// byte offset into a [rows][128B] LDS tile, XOR-swizzled (G4)
__device__ __forceinline__ int swz128(int row, int byteoff) {
  return row * 128 + (byteoff ^ ((row & 7) << 4));
}
// chunk=4 tiles: qoff4(qt) = sum_{q<qt} ceil((q+1)/4)
__device__ __forceinline__ int qoff4(int qt) {
  int G = qt >> 2, rem = qt & 3;
  return 2 * G * (G + 1) + rem * (G + 1);
}
__device__ __forceinline__ f32x16 zero16() {
  f32x16 z;
#pragma unroll
  for (int i = 0; i < 16; ++i) z[i] = 0.f;
  return z;
}
// 3-input max (compiler fuses to v_max3_f32)
__device__ __forceinline__ float max3(float a, float b, float c) {
  return fmaxf(fmaxf(a, b), c);
}

// ---------------- prep: converts (8 elems/thread) + rope tables ----------------
__global__ __launch_bounds__(256) void prep_kernel(
    const float* __restrict__ x, const float* __restrict__ Wq,
    const float* __restrict__ Wk, const float* __restrict__ Wv,
    const float* __restrict__ Wo,
    ushort* __restrict__ xb, ushort* __restrict__ w1, ushort* __restrict__ wob,
    float* __restrict__ cosT, float* __restrict__ sinT) {
  unsigned b = blockIdx.x;
  if (b < 3072u) {
    unsigned i8 = (b * 256u + threadIdx.x) * 8u;
    const float* s;
    ushort* d;
    if (i8 < 2097152u) { s = x + i8; d = xb + i8; }
    else if (i8 < 3145728u) { s = Wq + (i8 - 2097152u); d = w1 + (i8 - 2097152u); }
    else if (i8 < 4194304u) { s = Wk + (i8 - 3145728u); d = w1 + (i8 - 2097152u); }
    else if (i8 < 5242880u) { s = Wv + (i8 - 4194304u); d = w1 + (i8 - 2097152u); }
    else { s = Wo + (i8 - 5242880u); d = wob + (i8 - 5242880u); }
    float4 v0 = *(const float4*)s;
    float4 v1 = *(const float4*)(s + 4);
    union { ushort h[8]; uint4 u; } o;
    o.h[0] = f2b(v0.x); o.h[1] = f2b(v0.y); o.h[2] = f2b(v0.z); o.h[3] = f2b(v0.w);
    o.h[4] = f2b(v1.x); o.h[5] = f2b(v1.y); o.h[6] = f2b(v1.z); o.h[7] = f2b(v1.w);
    *(uint4*)d = o.u;
    return;
  }
  unsigned j = (b - 3072u) * 256u + threadIdx.x;  // 0..32767 : 2048 pos x 16 freqs
  int tt = (int)(j >> 4), jj = (int)(j & 15u);
  float inv = powf(10000.0f, -(float)(2 * jj) * (1.0f / 32.0f));
  float ang = (float)tt * inv;
  cosT[j] = cosf(ang);
  sinT[j] = sinf(ang);
}

// ---------------- transpose v -> vt[d][s] (512 blocks) ----------------
__global__ __launch_bounds__(256) void transv_kernel(const ushort* __restrict__ qkv,
                                                     ushort* __restrict__ vt) {
  __shared__ __align__(16) ushort tile[64][80];
  const int t = threadIdx.x;
  const int bb = (int)blockIdx.x;  // 0..511 : (d0 16) x (s0 32)
  const int d0 = (bb & 15) * 64, s0 = (bb >> 4) * 64;
#pragma unroll
  for (int p = 0; p < 2; ++p) {
    int sl = p * 32 + (t >> 3), d8 = (t & 7) * 8;
    uint4 v = *(const uint4*)(qkv + (size_t)(s0 + sl) * 3072 + 2048 + d0 + d8);
    *(uint4*)(&tile[sl][d8]) = v;
  }
  __syncthreads();
#pragma unroll
  for (int p = 0; p < 2; ++p) {
    int dl = p * 32 + (t >> 3), s8 = (t & 7) * 8;
    union { ushort h[8]; uint4 u; } tmp;
#pragma unroll
    for (int jj = 0; jj < 8; ++jj) tmp.h[jj] = tile[s8 + jj][dl];
    *(uint4*)(vt + (size_t)(d0 + dl) * 2048 + s0 + s8) = tmp.u;
  }
}

// ---------------- GEMM: C[M,N] = A[M,K].B[N,K]^T, tile BM x BN, BK=64 ----------------
// 4 waves 2x2; wave tile (BM/2)x(BN/2). global_load_lds with pre-swizzled source
// (rule #21). One barrier pair per 64-K round. XCD-chunked block remap (T1).
// ROPE: fused interleaved rope on cols < 2048 (C-layout col=lane&15 puts the
// (2u,2u+1) pair in lanes l, l^1 of the same row -> shfl_xor(v,1) + cos/sin fma).
template <int BM, int BN, int ROPE>
__global__ __launch_bounds__(256) void gemm_bt(const ushort* __restrict__ A,
                                               const ushort* __restrict__ B,
                                               void* __restrict__ C, int M, int N, int K,
                                               int out_bf16,
                                               const float* __restrict__ cosT,
                                               const float* __restrict__ sinT) {
  __shared__ __align__(16) ushort As[BM * 64];  // [BM][64], swizzled content
  __shared__ __align__(16) ushort Bs[BN * 64];
  const int t = threadIdx.x, lane = t & 63, w = t >> 6;
  const int g = lane >> 4, r = lane & 15;
  const int wr = w >> 1, wc = w & 1;
  // XCD-chunked remap (bijective when nwg % 8 == 0; else identity)
  const int nbx = gridDim.x, nwg = gridDim.x * gridDim.y;
  int bid = blockIdx.x + nbx * blockIdx.y;
  if ((nwg & 7) == 0) bid = (bid & 7) * (nwg >> 3) + (bid >> 3);
  const int m0 = (bid / nbx) * BM, n0 = (bid % nbx) * BN;
  constexpr int AM = BM / 32, AN = BN / 32;

  f32x4 acc[AM][AN];
#pragma unroll
  for (int i = 0; i < AM; ++i)
#pragma unroll
    for (int j = 0; j < AN; ++j) acc[i][j] = (f32x4){0.f, 0.f, 0.f, 0.f};

  for (int k0 = 0; k0 < K; k0 += 64) {
    __syncthreads();
#pragma unroll
    for (int p = 0; p < BM / 32; ++p) {
      int idx = p * 256 + t;
      int row = idx >> 3;                              // 8 chunks of 16B per 128B row
      int bo = ((idx & 7) * 16) ^ ((row & 7) << 4);    // pre-swizzled source byte
      GLOAD16(A + (size_t)(m0 + row) * K + k0 + (bo >> 1), As + idx * 8);
    }
#pragma unroll
    for (int p = 0; p < BN / 32; ++p) {
      int idx = p * 256 + t;
      int row = idx >> 3;
      int bo = ((idx & 7) * 16) ^ ((row & 7) << 4);
      GLOAD16(B + (size_t)(n0 + row) * K + k0 + (bo >> 1), Bs + idx * 8);
    }
    __syncthreads();  // drains vmcnt -> both 32-K halves staged
#pragma unroll
    for (int ks = 0; ks < 2; ++ks) {
      bf16x8 af[AM], bfr[AN];
#pragma unroll
      for (int i = 0; i < AM; ++i)
        af[i] = __builtin_bit_cast(bf16x8, *(const uint4*)((const char*)As + swz128(wr * (BM / 2) + i * 16 + r, (ks * 32 + g * 8) * 2)));
#pragma unroll
      for (int i = 0; i < AN; ++i)
        bfr[i] = __builtin_bit_cast(bf16x8, *(const uint4*)((const char*)Bs + swz128(wc * (BN / 2) + i * 16 + r, (ks * 32 + g * 8) * 2)));
#pragma unroll
      for (int mi = 0; mi < AM; ++mi)
#pragma unroll
        for (int ni = 0; ni < AN; ++ni)
          acc[mi][ni] = __builtin_amdgcn_mfma_f32_16x16x32_bf16(af[mi], bfr[ni], acc[mi][ni], 0, 0, 0);
    }
  }
  const bool do_rope = ROPE && (n0 < 2048);  // block-uniform
#pragma unroll
  for (int mi = 0; mi < AM; ++mi)
#pragma unroll
    for (int ni = 0; ni < AN; ++ni) {
      const int jj = ((ni * 16 + r) & 31) >> 1;  // rope freq index for this col
#pragma unroll
      for (int e = 0; e < 4; ++e) {
        int row = m0 + wr * (BM / 2) + mi * 16 + g * 4 + e;
        int col = n0 + wc * (BN / 2) + ni * 16 + r;
        float v = acc[mi][ni][e];
        if (do_rope) {
          float pr = __shfl_xor(v, 1);  // partner of interleaved pair (same row)
          float cc = cosT[row * 16 + jj], sn = sinT[row * 16 + jj];
          v = (r & 1) ? (pr * sn + v * cc) : (v * cc - pr * sn);
        }
        if (out_bf16) ((ushort*)C)[(size_t)row * N + col] = f2b(v);
        else ((float*)C)[(size_t)row * N + col] = v;
      }
    }
}

// ---------------- split-KV flash attention: 32x32 swapped-operand partials ----------------
// 1D grid 2304, XCD-chunked: id' = (id&7)*288 + (id>>3) -> each XCD owns 2 heads
// (K/V panels stay in that XCD's L2). 4 waves: wave w: sub = w&1, qhalf = w>>1.
// S^T = mfma(K, Q): lane holds P-column for its q-row -> in-lane softmax.
// P packed to bf16 in-register (cvt_pk + permlane32_swap), O^T = mfma(V^T, P).
// K/V staged via global_load_lds, pre-swizzled source (rule #21).
#define ATTN_STAGE(kt_, Kb, Vb)                                                         \
  do {                                                                                  \
    _Pragma("unroll") for (int p_ = 0; p_ < 2; ++p_) {                                  \
      int idx_ = (p_ * 4 + w) * 64 + lane;                                              \
      int row_ = idx_ >> 3;                                                             \
      int kbs_ = ((idx_ & 7) * 16) ^ ((row_ & 7) << 4);                                 \
      const ushort* gk_ = qkv + (size_t)((kt_) * 64 + row_) * 3072 + 1024 + h * 64 + (kbs_ >> 1); \
      const ushort* gv_ = vt + (size_t)(h * 64 + row_) * 2048 + (kt_) * 64 + (kbs_ >> 1);         \
      GLOAD16(gk_, (Kb) + (p_ * 4 + w) * 512);                                          \
      GLOAD16(gv_, (Vb) + (p_ * 4 + w) * 512);                                          \
    }                                                                                   \
  } while (0)

__global__ __launch_bounds__(256, 3) void attn_split_kernel(
    const ushort* __restrict__ qkv, const ushort* __restrict__ vt,
    ushort* __restrict__ pOh, float* __restrict__ pML) {
  __shared__ __align__(16) ushort Ks[2][64 * 64];  // [tile][kv row][64ch], swizzled content
  __shared__ __align__(16) ushort Vs[2][64 * 64];  // [tile][d][kv], swizzled content

  // XCD-chunked remap of 1D id, then decode (h, qt, c)
  const int id2 = (blockIdx.x & 7) * 288 + (blockIdx.x >> 3);
  const int h = id2 / 144;
  int wi = id2 % 144, qt = 0, c = 0;
  for (int q = 0; q < 32; ++q) {
    int nc = (q >> 2) + 1;
    if (wi < nc) { qt = q; c = wi; break; }
    wi -= nc;
  }
  const int pid = h * 144 + qoff4(qt) + c;
  const int t = threadIdx.x, lane = t & 63, w = t >> 6;
  const int sub = w & 1, qh = w >> 1;
  const int ql = lane & 31, g1 = lane >> 5;
  const int qa = qt * 64 + qh * 32 + ql;  // absolute q row for this lane

  // Q as B-operand: B[q=lane&31][ch = chain*16 + g1*8 + j]
  bf16x8 qf0 = __builtin_bit_cast(bf16x8, *(const uint4*)(qkv + (size_t)qa * 3072 + h * 64 + sub * 32 + g1 * 8));
  bf16x8 qf1 = __builtin_bit_cast(bf16x8, *(const uint4*)(qkv + (size_t)qa * 3072 + h * 64 + sub * 32 + 16 + g1 * 8));

  // hoisted loop-invariant LDS byte offsets
  const int koff0a = swz128(ql, (sub * 32 + g1 * 8) * 2);
  const int koff0b = swz128(32 + ql, (sub * 32 + g1 * 8) * 2);
  const int koff1a = swz128(ql, (sub * 32 + 16 + g1 * 8) * 2);
  const int koff1b = swz128(32 + ql, (sub * 32 + 16 + g1 * 8) * 2);
  int voffa[4], voffb[4];
#pragma unroll
  for (int ks = 0; ks < 4; ++ks) {
    voffa[ks] = swz128(ql, (ks * 16 + g1 * 8) * 2);
    voffb[ks] = swz128(32 + ql, (ks * 16 + g1 * 8) * 2);
  }

  f32x16 O0 = zero16(), O1 = zero16();  // O^T[d][q = lane&31]
  float mm = -1e30f, lsum = 0.f;

  auto do_tile = [&](int kt, const ushort* Ksb, const ushort* Vsb) {
    const char* Kc = (const char*)Ksb;
    const char* Vc = (const char*)Vsb;

    // S^T[kv][q]: A = K (rows kv), B = Q (cols q)
    f32x16 s0 = zero16(), s1 = zero16();
    {
      bf16x8 ka = __builtin_bit_cast(bf16x8, *(const uint4*)(Kc + koff0a));
      bf16x8 kb = __builtin_bit_cast(bf16x8, *(const uint4*)(Kc + koff0b));
      bf16x8 kc = __builtin_bit_cast(bf16x8, *(const uint4*)(Kc + koff1a));
      bf16x8 kd = __builtin_bit_cast(bf16x8, *(const uint4*)(Kc + koff1b));
      __builtin_amdgcn_s_setprio(1);
      s0 = __builtin_amdgcn_mfma_f32_32x32x16_bf16(ka, qf0, s0, 0, 0, 0);
      s1 = __builtin_amdgcn_mfma_f32_32x32x16_bf16(kb, qf0, s1, 0, 0, 0);
      s0 = __builtin_amdgcn_mfma_f32_32x32x16_bf16(kc, qf1, s0, 0, 0, 0);
      s1 = __builtin_amdgcn_mfma_f32_32x32x16_bf16(kd, qf1, s1, 0, 0, 0);
      __builtin_amdgcn_s_setprio(0);
    }

    // causal mask (raw S units); kv_local = (rg&3) + 4*g1 + 8*(rg>>2) + 32*kvb
    if (kt == qt) {
      const int lim = qh * 32 + ql;
#pragma unroll
      for (int rg = 0; rg < 16; ++rg) {
        int kv0 = (rg & 3) + 4 * g1 + 8 * (rg >> 2);
        if (kv0 > lim) s0[rg] = -1e30f;
        if (kv0 + 32 > lim) s1[rg] = -1e30f;
      }
    }

    // row max: max3 tree (depth ~4); element access only
    float a0 = max3(s0[0], s0[1], s0[2]);
    float a1 = max3(s0[3], s0[4], s0[5]);
    float a2 = max3(s0[6], s0[7], s0[8]);
    float a3 = max3(s0[9], s0[10], s0[11]);
    float a4 = max3(s0[12], s0[13], s0[14]);
    float b0 = max3(s1[0], s1[1], s1[2]);
    float b1 = max3(s1[3], s1[4], s1[5]);
    float b2 = max3(s1[6], s1[7], s1[8]);
    float b3 = max3(s1[9], s1[10], s1[11]);
    float b4 = max3(s1[12], s1[13], s1[14]);
    float c0 = max3(a0, a1, a2);
    float c1 = max3(a3, a4, s0[15]);
    float c2 = max3(b0, b1, b2);
    float c3 = max3(b3, b4, s1[15]);
    float rm = fmaxf(max3(c0, c1, c2), c3);
    rm = fmaxf(rm, __shfl_xor(rm, 32));

    // T13 defer-max: only rescale when max grew beyond THR
    if (!__all(rm - mm <= DMAX_THR)) {
      float mn = fmaxf(mm, rm);
      float es = exp2f((mm - mn) * C1EXP);
      mm = mn;
      lsum *= es;
      O0 *= es;
      O1 *= es;
    }

    // exp section: scalar fma/exp2; 4-way interleaved partial sums (depth 8)
    const float mnC = mm * C1EXP;
    float pa = 0.f, pb = 0.f, pc = 0.f, pd = 0.f;
#pragma unroll
    for (int rg = 0; rg < 16; rg += 2) {
      float p00 = exp2f(__builtin_fmaf(s0[rg], C1EXP, -mnC));
      float p01 = exp2f(__builtin_fmaf(s0[rg + 1], C1EXP, -mnC));
      float p10 = exp2f(__builtin_fmaf(s1[rg], C1EXP, -mnC));
      float p11 = exp2f(__builtin_fmaf(s1[rg + 1], C1EXP, -mnC));
      s0[rg] = p00; s0[rg + 1] = p01;
      s1[rg] = p10; s1[rg + 1] = p11;
      pa += p00; pb += p01; pc += p10; pd += p11;
    }
    float ps = (pa + pb) + (pc + pd);
    ps += __shfl_xor(ps, 32);
    lsum += ps;

    // pack P -> bf16 pairs: pk[kvb][q2][t] covers kv = 32kvb + 8q2 + 4g1 + 2t + {0,1}
    unsigned pk[2][4][2];
#pragma unroll
    for (int q2 = 0; q2 < 4; ++q2) {
      float x0 = s0[4 * q2 + 0], x1 = s0[4 * q2 + 1], x2 = s0[4 * q2 + 2], x3 = s0[4 * q2 + 3];
      float y0 = s1[4 * q2 + 0], y1 = s1[4 * q2 + 1], y2 = s1[4 * q2 + 2], y3 = s1[4 * q2 + 3];
      asm("v_cvt_pk_bf16_f32 %0, %1, %2" : "=v"(pk[0][q2][0]) : "v"(x0), "v"(x1));
      asm("v_cvt_pk_bf16_f32 %0, %1, %2" : "=v"(pk[0][q2][1]) : "v"(x2), "v"(x3));
      asm("v_cvt_pk_bf16_f32 %0, %1, %2" : "=v"(pk[1][q2][0]) : "v"(y0), "v"(y1));
      asm("v_cvt_pk_bf16_f32 %0, %1, %2" : "=v"(pk[1][q2][1]) : "v"(y2), "v"(y3));
    }
#pragma unroll
    for (int kvb = 0; kvb < 2; ++kvb) {
      asm volatile("v_permlane32_swap_b32 %0, %1" : "+v"(pk[kvb][0][0]), "+v"(pk[kvb][1][0]));
      asm volatile("v_permlane32_swap_b32 %0, %1" : "+v"(pk[kvb][0][1]), "+v"(pk[kvb][1][1]));
      asm volatile("v_permlane32_swap_b32 %0, %1" : "+v"(pk[kvb][2][0]), "+v"(pk[kvb][3][0]));
      asm volatile("v_permlane32_swap_b32 %0, %1" : "+v"(pk[kvb][2][1]), "+v"(pk[kvb][3][1]));
    }

    // PV: O^T[d][q] += V^T[d][kv] . P[kv][q]; ks covers kv 16-block
#pragma unroll
    for (int ks = 0; ks < 4; ++ks) {
      const int kvb = ks >> 1, kshi = ks & 1;
      uint4 pu;
      pu.x = pk[kvb][2 * kshi][0];
      pu.y = pk[kvb][2 * kshi][1];
      pu.z = pk[kvb][2 * kshi + 1][0];
      pu.w = pk[kvb][2 * kshi + 1][1];
      bf16x8 pf = __builtin_bit_cast(bf16x8, pu);
      bf16x8 v0 = __builtin_bit_cast(bf16x8, *(const uint4*)(Vc + voffa[ks]));
      bf16x8 v1 = __builtin_bit_cast(bf16x8, *(const uint4*)(Vc + voffb[ks]));
      __builtin_amdgcn_s_setprio(1);
      O0 = __builtin_amdgcn_mfma_f32_32x32x16_bf16(v0, pf, O0, 0, 0, 0);
      O1 = __builtin_amdgcn_mfma_f32_32x32x16_bf16(v1, pf, O1, 0, 0, 0);
      __builtin_amdgcn_s_setprio(0);
    }
  };

  const int ktb = c * 4;
  const int kte = min(ktb + 4, qt + 1);
  for (int kt0 = ktb; kt0 < kte; kt0 += 2) {
    const bool two = (kt0 + 1 < kte);  // block-uniform
    __syncthreads();                   // previous round's LDS reads done
    ATTN_STAGE(kt0, Ks[0], Vs[0]);
    if (two) ATTN_STAGE(kt0 + 1, Ks[1], Vs[1]);
    __syncthreads();                   // drains vmcnt -> both tiles staged
    do_tile(kt0, Ks[0], Vs[0]);
    if (two) do_tile(kt0 + 1, Ks[1], Vs[1]);
  }

  // write partials: pML fp32, pO fp16. O^T: d = dblk*32 + (rg&3) + 4g1 + 8(rg>>2), q = ql.
  const int qrow = qh * 32 + ql;
  float* pml = pML + (size_t)pid * 256 + sub * 128;
  if (g1 == 0) {
    pml[qrow] = mm;
    pml[64 + qrow] = lsum;
  }
  ushort* po = pOh + ((size_t)(pid * 2 + sub) * 64 + qrow) * 64;
#pragma unroll
  for (int q2 = 0; q2 < 4; ++q2) {
    uint2 u0, u1;
    u0.x = (unsigned)f2h(O0[4 * q2 + 0]) | ((unsigned)f2h(O0[4 * q2 + 1]) << 16);
    u0.y = (unsigned)f2h(O0[4 * q2 + 2]) | ((unsigned)f2h(O0[4 * q2 + 3]) << 16);
    u1.x = (unsigned)f2h(O1[4 * q2 + 0]) | ((unsigned)f2h(O1[4 * q2 + 1]) << 16);
    u1.y = (unsigned)f2h(O1[4 * q2 + 2]) | ((unsigned)f2h(O1[4 * q2 + 3]) << 16);
    *(uint2*)(po + q2 * 8 + g1 * 4) = u0;
    *(uint2*)(po + 32 + q2 * 8 + g1 * 4) = u1;
  }
}

// ---------------- combine partials + diff + RMSNorm ----------------
// block = (qt, h), 256 threads: thread t -> row = t>>2, quad = t&3 (16 ch each)
__global__ __launch_bounds__(256) void combine_kernel(
    const ushort* __restrict__ pOh, const float* __restrict__ pML,
    const float* __restrict__ lq1, const float* __restrict__ lk1,
    const float* __restrict__ lq2, const float* __restrict__ lk2,
    const float* __restrict__ gamma, ushort* __restrict__ attn_out) {
  const int qt = blockIdx.x, h = blockIdx.y;
  const int nc = (qt >> 2) + 1;
  const int pbase = h * 144 + qoff4(qt);
  const int t = threadIdx.x, row = t >> 2, quad = t & 3;
  const int lane = t & 63;

  // lambda = exp(lq1.lk1) - exp(lq2.lk2) + LAM_INIT
  float lam;
  {
    int d = lane & 31;
    float a1 = lq1[d] * lk1[d];
    float a2 = lq2[d] * lk2[d];
#pragma unroll
    for (int m = 16; m >= 1; m >>= 1) {
      a1 += __shfl_xor(a1, m);
      a2 += __shfl_xor(a2, m);
    }
    lam = expf(a1) - expf(a2) + LAM_INIT;
  }

  float M[2] = {-1e30f, -1e30f};
  for (int c = 0; c < nc; ++c) {
    const float* ml = pML + (size_t)(pbase + c) * 256;
    M[0] = fmaxf(M[0], ml[row]);
    M[1] = fmaxf(M[1], ml[128 + row]);
  }
  float L[2] = {0.f, 0.f};
  float acc[2][16];
#pragma unroll
  for (int s = 0; s < 2; ++s)
#pragma unroll
    for (int v = 0; v < 16; ++v) acc[s][v] = 0.f;

  for (int c = 0; c < nc; ++c) {
    const int pid = pbase + c;
    const float* ml = pML + (size_t)pid * 256;
#pragma unroll
    for (int s = 0; s < 2; ++s) {
      float mc = ml[s * 128 + row];
      float lc = ml[s * 128 + 64 + row];
      float wgt = exp2f((mc - M[s]) * C1EXP);  // raw-S units
      L[s] += lc * wgt;
      const ushort* op = pOh + ((size_t)(pid * 2 + s) * 64 + row) * 64 + quad * 16;
      uint4 ua = *(const uint4*)op;
      uint4 ub = *(const uint4*)(op + 8);
      unsigned uu[8] = {ua.x, ua.y, ua.z, ua.w, ub.x, ub.y, ub.z, ub.w};
#pragma unroll
      for (int j = 0; j < 8; ++j) {
        acc[s][2 * j + 0] += h2f((ushort)(uu[j] & 0xffffu)) * wgt;
        acc[s][2 * j + 1] += h2f((ushort)(uu[j] >> 16)) * wgt;
      }
    }
  }

  float inv0 = 1.f / L[0], inv1 = 1.f / L[1];
  float wv[16], ss = 0.f;
#pragma unroll
  for (int j = 0; j < 16; ++j) {
    float val = acc[0][j] * inv0 - lam * (acc[1][j] * inv1);
    wv[j] = val;
    ss += val * val;
  }
  ss += __shfl_xor(ss, 1);
  ss += __shfl_xor(ss, 2);
  float scl = rsqrtf(ss * (1.f / 64.f) + 1e-5f) * ONE_M_LI;

  union { ushort hs[16]; uint4 u[2]; } outp;
#pragma unroll
  for (int j = 0; j < 16; ++j)
    outp.hs[j] = f2b(wv[j] * scl * gamma[quad * 16 + j]);
  uint4* dst = (uint4*)(attn_out + (size_t)(qt * 64 + row) * 1024 + h * 64 + quad * 16);
  dst[0] = outp.u[0];
  dst[1] = outp.u[1];
}

extern "C" void kernel_launch(void* const* d_in, const int* in_sizes, int n_in,
                              void* d_out, int out_size, void* d_ws, size_t ws_size,
                              hipStream_t stream) {
  const float* x = (const float*)d_in[0];
  const float* Wq = (const float*)d_in[1];
  const float* Wk = (const float*)d_in[2];
  const float* Wv = (const float*)d_in[3];
  const float* Wo = (const float*)d_in[4];
  const float* lq1 = (const float*)d_in[5];
  const float* lk1 = (const float*)d_in[6];
  const float* lq2 = (const float*)d_in[7];
  const float* lk2 = (const float*)d_in[8];
  const float* gamma = (const float*)d_in[9];
  (void)in_sizes; (void)n_in; (void)out_size; (void)ws_size;

  char* ws = (char*)d_ws;
  ushort* xb = (ushort*)(ws);
  ushort* w1 = (ushort*)(ws + (4ull << 20));
  ushort* wob = (ushort*)(ws + (10ull << 20));
  ushort* qkv = (ushort*)(ws + (12ull << 20));
  ushort* vt = (ushort*)(ws + (24ull << 20));
  ushort* atn = (ushort*)(ws + (28ull << 20));
  float* cosT = (float*)(ws + (32ull << 20));
  float* sinT = (float*)(ws + (32ull << 20) + 2048 * 16 * 4);
  const size_t pO_off = (33ull << 20);
  const size_t pml_off = pO_off + 2304ull * 2 * 64 * 64 * 2;  // fp16 partials
  ushort* pOh = (ushort*)(ws + pO_off);
  float* pML = (float*)(ws + pml_off);

  prep_kernel<<<3200, 256, 0, stream>>>(x, Wq, Wk, Wv, Wo, xb, w1, wob, cosT, sinT);
  gemm_bt<64, 128, 1><<<dim3(24, 32), 256, 0, stream>>>(xb, w1, (void*)qkv, 2048, 3072, 1024, 1, cosT, sinT);
  transv_kernel<<<512, 256, 0, stream>>>(qkv, vt);
  attn_split_kernel<<<2304, 256, 0, stream>>>(qkv, vt, pOh, pML);
  combine_kernel<<<dim3(32, 16), 256, 0, stream>>>(pOh, pML, lq1, lk1, lq2, lk2, gamma, atn);
  gemm_bt<64, 64, 0><<<dim3(16, 32), 256, 0, stream>>>(atn, wob, d_out, 2048, 1024, 1024, 0, nullptr, nullptr);
}

// Round 11
// 93.055 us; speedup vs baseline: 1.0711x; 1.0711x over previous
//
#include <hip/hip_runtime.h>
#include <hip/hip_bf16.h>
#include <math.h>

// Differential attention, bf16 MFMA pipeline, split-KV flash attention with
// swapped-operand 32x32x16 MFMA softmax (T12). R11: revert gemm XCD remap
// (unverified); fuse V-transpose into gemm1 epilogue (V blocks write vt[d][s]
// via in-LDS transpose; transv kernel + qkv V-writes eliminated). Attn keeps
// verified XCD swizzle (FETCH 35->6.2 MB) + fused rope stays.
// ws layout (bytes):
//   [0,4M)    xb      x as bf16             2048x1024
//   [4M,10M)  w1      [Wq;Wk;Wv] bf16       3072x1024
//   [10M,12M) wob     Wo bf16               1024x1024
//   [12M,24M) qkv     bf16, row stride 3072 (q|k|v); rope applied; V region unused
//   [24M,28M) vt      v transposed bf16     1024x2048  vt[d][s]
//   [28M,32M) atn     normalized wv bf16    2048x1024
//   [32M,+256K) cos/sin tables fp32         2048x16 each
//   [33M,+37.75M)  pOh  fp16 partial O  [2304 pids][2 subs][64 q][64 d]
//   [33M+37.75M,+2.36M) pML fp32 partial m,l [2304][2][2][64]
// pid = h*144 + qoff4(qt) + chunk;  chunk = 256 kv rows (4 k-tiles of 64)

typedef __bf16 bf16x8 __attribute__((ext_vector_type(8)));
typedef float f32x4 __attribute__((ext_vector_type(4)));
typedef float f32x16 __attribute__((ext_vector_type(16)));

#define LOG2E 1.4426950408889634f
#define SCALE 0.17677669529663687f /* 1/sqrt(32) */
#define C1EXP 0.25506100319239545f /* SCALE*LOG2E : exp2 scale for raw S */
#define DMAX_THR 31.36f            /* 8 / C1EXP : defer-max threshold, raw-S units */
#define LAM_INIT 0.783605766532f
#define ONE_M_LI 0.216394233468f

// async global->LDS, 16B per lane; lds base must be wave-uniform (lane scatters +l*16)
#define GLOAD16(g, l)                                                              \
  __builtin_amdgcn_global_load_lds((const __attribute__((address_space(1))) void*)(g), \
                                   (__attribute__((address_space(3))) void*)(l), 16, 0, 0)

__device__ __forceinline__ ushort f2b(float f) {
  unsigned u = __builtin_bit_cast(unsigned, f);
  u += 0x7fffu + ((u >> 16) & 1u);
  return (ushort)(u >> 16);
}
__device__ __forceinline__ float b2f(ushort h) {
  return __builtin_bit_cast(float, ((unsigned)h) << 16);
}
__device__ __forceinline__ ushort f2h(float f) {
  _Float16 h = (_Float16)f;
  return __builtin_bit_cast(ushort, h);
}
__device__ __forceinline__ float h2f(ushort u) {
  return (float)__builtin_bit_cast(_Float16, u);
}
// byte offset into a [rows][128B] LDS tile, XOR-swizzled (G4)
__device__ __forceinline__ int swz128(int row, int byteoff) {
  return row * 128 + (byteoff ^ ((row & 7) << 4));
}
// chunk=4 tiles: qoff4(qt) = sum_{q<qt} ceil((q+1)/4)
__device__ __forceinline__ int qoff4(int qt) {
  int G = qt >> 2, rem = qt & 3;
  return 2 * G * (G + 1) + rem * (G + 1);
}
__device__ __forceinline__ f32x16 zero16() {
  f32x16 z;
#pragma unroll
  for (int i = 0; i < 16; ++i) z[i] = 0.f;
  return z;
}
// 3-input max (compiler fuses to v_max3_f32)
__device__ __forceinline__ float max3(float a, float b, float c) {
  return fmaxf(fmaxf(a, b), c);
}

// ---------------- prep: converts (8 elems/thread) + rope tables ----------------
__global__ __launch_bounds__(256) void prep_kernel(
    const float* __restrict__ x, const float* __restrict__ Wq,
    const float* __restrict__ Wk, const float* __restrict__ Wv,
    const float* __restrict__ Wo,
    ushort* __restrict__ xb, ushort* __restrict__ w1, ushort* __restrict__ wob,
    float* __restrict__ cosT, float* __restrict__ sinT) {
  unsigned b = blockIdx.x;
  if (b < 3072u) {
    unsigned i8 = (b * 256u + threadIdx.x) * 8u;
    const float* s;
    ushort* d;
    if (i8 < 2097152u) { s = x + i8; d = xb + i8; }
    else if (i8 < 3145728u) { s = Wq + (i8 - 2097152u); d = w1 + (i8 - 2097152u); }
    else if (i8 < 4194304u) { s = Wk + (i8 - 3145728u); d = w1 + (i8 - 2097152u); }
    else if (i8 < 5242880u) { s = Wv + (i8 - 4194304u); d = w1 + (i8 - 2097152u); }
    else { s = Wo + (i8 - 5242880u); d = wob + (i8 - 5242880u); }
    float4 v0 = *(const float4*)s;
    float4 v1 = *(const float4*)(s + 4);
    union { ushort h[8]; uint4 u; } o;
    o.h[0] = f2b(v0.x); o.h[1] = f2b(v0.y); o.h[2] = f2b(v0.z); o.h[3] = f2b(v0.w);
    o.h[4] = f2b(v1.x); o.h[5] = f2b(v1.y); o.h[6] = f2b(v1.z); o.h[7] = f2b(v1.w);
    *(uint4*)d = o.u;
    return;
  }
  unsigned j = (b - 3072u) * 256u + threadIdx.x;  // 0..32767 : 2048 pos x 16 freqs
  int tt = (int)(j >> 4), jj = (int)(j & 15u);
  float inv = powf(10000.0f, -(float)(2 * jj) * (1.0f / 32.0f));
  float ang = (float)tt * inv;
  cosT[j] = cosf(ang);
  sinT[j] = sinf(ang);
}

// ---------------- GEMM: C[M,N] = A[M,K].B[N,K]^T, tile BM x BN, BK=64 ----------------
// 4 waves 2x2; wave tile (BM/2)x(BN/2). global_load_lds with pre-swizzled source
// (rule #21). One barrier pair per 64-K round.
// FUSE=1 (gemm1): cols<2048 get interleaved RoPE (shfl_xor(v,1) pair in-row);
// cols>=2048 (V) are transposed in-LDS and written to vt[d][s]; qkv V skipped.
template <int BM, int BN, int FUSE>
__global__ __launch_bounds__(256) void gemm_bt(const ushort* __restrict__ A,
                                               const ushort* __restrict__ B,
                                               void* __restrict__ C, int M, int N, int K,
                                               int out_bf16,
                                               const float* __restrict__ cosT,
                                               const float* __restrict__ sinT,
                                               ushort* __restrict__ vt) {
  __shared__ __align__(16) ushort sh[BM * 64 + BN * 64];  // As | Bs (also V-transpose buf)
  ushort* As = sh;
  ushort* Bs = sh + BM * 64;
  const int t = threadIdx.x, lane = t & 63, w = t >> 6;
  const int g = lane >> 4, r = lane & 15;
  const int wr = w >> 1, wc = w & 1;
  const int m0 = blockIdx.y * BM, n0 = blockIdx.x * BN;
  constexpr int AM = BM / 32, AN = BN / 32;

  f32x4 acc[AM][AN];
#pragma unroll
  for (int i = 0; i < AM; ++i)
#pragma unroll
    for (int j = 0; j < AN; ++j) acc[i][j] = (f32x4){0.f, 0.f, 0.f, 0.f};

  for (int k0 = 0; k0 < K; k0 += 64) {
    __syncthreads();
#pragma unroll
    for (int p = 0; p < BM / 32; ++p) {
      int idx = p * 256 + t;
      int row = idx >> 3;                              // 8 chunks of 16B per 128B row
      int bo = ((idx & 7) * 16) ^ ((row & 7) << 4);    // pre-swizzled source byte
      GLOAD16(A + (size_t)(m0 + row) * K + k0 + (bo >> 1), As + idx * 8);
    }
#pragma unroll
    for (int p = 0; p < BN / 32; ++p) {
      int idx = p * 256 + t;
      int row = idx >> 3;
      int bo = ((idx & 7) * 16) ^ ((row & 7) << 4);
      GLOAD16(B + (size_t)(n0 + row) * K + k0 + (bo >> 1), Bs + idx * 8);
    }
    __syncthreads();  // drains vmcnt -> both 32-K halves staged
#pragma unroll
    for (int ks = 0; ks < 2; ++ks) {
      bf16x8 af[AM], bfr[AN];
#pragma unroll
      for (int i = 0; i < AM; ++i)
        af[i] = __builtin_bit_cast(bf16x8, *(const uint4*)((const char*)As + swz128(wr * (BM / 2) + i * 16 + r, (ks * 32 + g * 8) * 2)));
#pragma unroll
      for (int i = 0; i < AN; ++i)
        bfr[i] = __builtin_bit_cast(bf16x8, *(const uint4*)((const char*)Bs + swz128(wc * (BN / 2) + i * 16 + r, (ks * 32 + g * 8) * 2)));
#pragma unroll
      for (int mi = 0; mi < AM; ++mi)
#pragma unroll
        for (int ni = 0; ni < AN; ++ni)
          acc[mi][ni] = __builtin_amdgcn_mfma_f32_16x16x32_bf16(af[mi], bfr[ni], acc[mi][ni], 0, 0, 0);
    }
  }

  if (FUSE && n0 >= 2048) {
    // V block: transpose acc in LDS, write vt[d][s] coalesced. qkv V skipped.
    __syncthreads();  // MFMA LDS reads done; reuse sh as [128][72] buffer
    ushort* lt = sh;
#pragma unroll
    for (int mi = 0; mi < AM; ++mi)
#pragma unroll
      for (int ni = 0; ni < AN; ++ni)
#pragma unroll
        for (int e = 0; e < 4; ++e) {
          int sl = wr * (BM / 2) + mi * 16 + g * 4 + e;  // s_local 0..63
          int dl = wc * (BN / 2) + ni * 16 + r;          // d_local 0..127
          lt[dl * 72 + sl] = f2b(acc[mi][ni][e]);
        }
    __syncthreads();
#pragma unroll
    for (int p = 0; p < 4; ++p) {
      int id = p * 256 + t;
      int dl = id >> 3, s8 = (id & 7) * 8;
      uint4 v = *(const uint4*)(lt + dl * 72 + s8);
      *(uint4*)(vt + (size_t)(n0 - 2048 + dl) * 2048 + m0 + s8) = v;
    }
    return;
  }

  const bool do_rope = FUSE && (n0 < 2048);  // block-uniform
#pragma unroll
  for (int mi = 0; mi < AM; ++mi)
#pragma unroll
    for (int ni = 0; ni < AN; ++ni) {
      const int jj = ((ni * 16 + r) & 31) >> 1;  // rope freq index for this col
#pragma unroll
      for (int e = 0; e < 4; ++e) {
        int row = m0 + wr * (BM / 2) + mi * 16 + g * 4 + e;
        int col = n0 + wc * (BN / 2) + ni * 16 + r;
        float v = acc[mi][ni][e];
        if (do_rope) {
          float pr = __shfl_xor(v, 1);  // partner of interleaved pair (same row)
          float cc = cosT[row * 16 + jj], sn = sinT[row * 16 + jj];
          v = (r & 1) ? (pr * sn + v * cc) : (v * cc - pr * sn);
        }
        if (out_bf16) ((ushort*)C)[(size_t)row * N + col] = f2b(v);
        else ((float*)C)[(size_t)row * N + col] = v;
      }
    }
}

// ---------------- split-KV flash attention: 32x32 swapped-operand partials ----------------
// 1D grid 2304, XCD-chunked: id' = (id&7)*288 + (id>>3) -> each XCD owns 2 heads
// (K/V panels stay in that XCD's L2; verified FETCH 35->6.2 MB). 4 waves: wave w:
// sub = w&1, qhalf = w>>1. S^T = mfma(K, Q): lane holds P-column for its q-row.
// P packed to bf16 in-register (cvt_pk + permlane32_swap), O^T = mfma(V^T, P).
// K/V staged via global_load_lds, pre-swizzled source (rule #21).
#define ATTN_STAGE(kt_, Kb, Vb)                                                         \
  do {                                                                                  \
    _Pragma("unroll") for (int p_ = 0; p_ < 2; ++p_) {                                  \
      int idx_ = (p_ * 4 + w) * 64 + lane;                                              \
      int row_ = idx_ >> 3;                                                             \
      int kbs_ = ((idx_ & 7) * 16) ^ ((row_ & 7) << 4);                                 \
      const ushort* gk_ = qkv + (size_t)((kt_) * 64 + row_) * 3072 + 1024 + h * 64 + (kbs_ >> 1); \
      const ushort* gv_ = vt + (size_t)(h * 64 + row_) * 2048 + (kt_) * 64 + (kbs_ >> 1);         \
      GLOAD16(gk_, (Kb) + (p_ * 4 + w) * 512);                                          \
      GLOAD16(gv_, (Vb) + (p_ * 4 + w) * 512);                                          \
    }                                                                                   \
  } while (0)

__global__ __launch_bounds__(256, 3) void attn_split_kernel(
    const ushort* __restrict__ qkv, const ushort* __restrict__ vt,
    ushort* __restrict__ pOh, float* __restrict__ pML) {
  __shared__ __align__(16) ushort Ks[2][64 * 64];  // [tile][kv row][64ch], swizzled content
  __shared__ __align__(16) ushort Vs[2][64 * 64];  // [tile][d][kv], swizzled content

  // XCD-chunked remap of 1D id, then decode (h, qt, c)
  const int id2 = (blockIdx.x & 7) * 288 + (blockIdx.x >> 3);
  const int h = id2 / 144;
  int wi = id2 % 144, qt = 0, c = 0;
  for (int q = 0; q < 32; ++q) {
    int nc = (q >> 2) + 1;
    if (wi < nc) { qt = q; c = wi; break; }
    wi -= nc;
  }
  const int pid = h * 144 + qoff4(qt) + c;
  const int t = threadIdx.x, lane = t & 63, w = t >> 6;
  const int sub = w & 1, qh = w >> 1;
  const int ql = lane & 31, g1 = lane >> 5;
  const int qa = qt * 64 + qh * 32 + ql;  // absolute q row for this lane

  // Q as B-operand: B[q=lane&31][ch = chain*16 + g1*8 + j]
  bf16x8 qf0 = __builtin_bit_cast(bf16x8, *(const uint4*)(qkv + (size_t)qa * 3072 + h * 64 + sub * 32 + g1 * 8));
  bf16x8 qf1 = __builtin_bit_cast(bf16x8, *(const uint4*)(qkv + (size_t)qa * 3072 + h * 64 + sub * 32 + 16 + g1 * 8));

  // hoisted loop-invariant LDS byte offsets
  const int koff0a = swz128(ql, (sub * 32 + g1 * 8) * 2);
  const int koff0b = swz128(32 + ql, (sub * 32 + g1 * 8) * 2);
  const int koff1a = swz128(ql, (sub * 32 + 16 + g1 * 8) * 2);
  const int koff1b = swz128(32 + ql, (sub * 32 + 16 + g1 * 8) * 2);
  int voffa[4], voffb[4];
#pragma unroll
  for (int ks = 0; ks < 4; ++ks) {
    voffa[ks] = swz128(ql, (ks * 16 + g1 * 8) * 2);
    voffb[ks] = swz128(32 + ql, (ks * 16 + g1 * 8) * 2);
  }

  f32x16 O0 = zero16(), O1 = zero16();  // O^T[d][q = lane&31]
  float mm = -1e30f, lsum = 0.f;

  auto do_tile = [&](int kt, const ushort* Ksb, const ushort* Vsb) {
    const char* Kc = (const char*)Ksb;
    const char* Vc = (const char*)Vsb;

    // S^T[kv][q]: A = K (rows kv), B = Q (cols q)
    f32x16 s0 = zero16(), s1 = zero16();
    {
      bf16x8 ka = __builtin_bit_cast(bf16x8, *(const uint4*)(Kc + koff0a));
      bf16x8 kb = __builtin_bit_cast(bf16x8, *(const uint4*)(Kc + koff0b));
      bf16x8 kc = __builtin_bit_cast(bf16x8, *(const uint4*)(Kc + koff1a));
      bf16x8 kd = __builtin_bit_cast(bf16x8, *(const uint4*)(Kc + koff1b));
      __builtin_amdgcn_s_setprio(1);
      s0 = __builtin_amdgcn_mfma_f32_32x32x16_bf16(ka, qf0, s0, 0, 0, 0);
      s1 = __builtin_amdgcn_mfma_f32_32x32x16_bf16(kb, qf0, s1, 0, 0, 0);
      s0 = __builtin_amdgcn_mfma_f32_32x32x16_bf16(kc, qf1, s0, 0, 0, 0);
      s1 = __builtin_amdgcn_mfma_f32_32x32x16_bf16(kd, qf1, s1, 0, 0, 0);
      __builtin_amdgcn_s_setprio(0);
    }

    // causal mask (raw S units); kv_local = (rg&3) + 4*g1 + 8*(rg>>2) + 32*kvb
    if (kt == qt) {
      const int lim = qh * 32 + ql;
#pragma unroll
      for (int rg = 0; rg < 16; ++rg) {
        int kv0 = (rg & 3) + 4 * g1 + 8 * (rg >> 2);
        if (kv0 > lim) s0[rg] = -1e30f;
        if (kv0 + 32 > lim) s1[rg] = -1e30f;
      }
    }

    // row max: max3 tree (depth ~4); element access only
    float a0 = max3(s0[0], s0[1], s0[2]);
    float a1 = max3(s0[3], s0[4], s0[5]);
    float a2 = max3(s0[6], s0[7], s0[8]);
    float a3 = max3(s0[9], s0[10], s0[11]);
    float a4 = max3(s0[12], s0[13], s0[14]);
    float b0 = max3(s1[0], s1[1], s1[2]);
    float b1 = max3(s1[3], s1[4], s1[5]);
    float b2 = max3(s1[6], s1[7], s1[8]);
    float b3 = max3(s1[9], s1[10], s1[11]);
    float b4 = max3(s1[12], s1[13], s1[14]);
    float c0 = max3(a0, a1, a2);
    float c1 = max3(a3, a4, s0[15]);
    float c2 = max3(b0, b1, b2);
    float c3 = max3(b3, b4, s1[15]);
    float rm = fmaxf(max3(c0, c1, c2), c3);
    rm = fmaxf(rm, __shfl_xor(rm, 32));

    // T13 defer-max: only rescale when max grew beyond THR
    if (!__all(rm - mm <= DMAX_THR)) {
      float mn = fmaxf(mm, rm);
      float es = exp2f((mm - mn) * C1EXP);
      mm = mn;
      lsum *= es;
      O0 *= es;
      O1 *= es;
    }

    // exp section: scalar fma/exp2; 4-way interleaved partial sums (depth 8)
    const float mnC = mm * C1EXP;
    float pa = 0.f, pb = 0.f, pc = 0.f, pd = 0.f;
#pragma unroll
    for (int rg = 0; rg < 16; rg += 2) {
      float p00 = exp2f(__builtin_fmaf(s0[rg], C1EXP, -mnC));
      float p01 = exp2f(__builtin_fmaf(s0[rg + 1], C1EXP, -mnC));
      float p10 = exp2f(__builtin_fmaf(s1[rg], C1EXP, -mnC));
      float p11 = exp2f(__builtin_fmaf(s1[rg + 1], C1EXP, -mnC));
      s0[rg] = p00; s0[rg + 1] = p01;
      s1[rg] = p10; s1[rg + 1] = p11;
      pa += p00; pb += p01; pc += p10; pd += p11;
    }
    float ps = (pa + pb) + (pc + pd);
    ps += __shfl_xor(ps, 32);
    lsum += ps;

    // pack P -> bf16 pairs: pk[kvb][q2][t] covers kv = 32kvb + 8q2 + 4g1 + 2t + {0,1}
    unsigned pk[2][4][2];
#pragma unroll
    for (int q2 = 0; q2 < 4; ++q2) {
      float x0 = s0[4 * q2 + 0], x1 = s0[4 * q2 + 1], x2 = s0[4 * q2 + 2], x3 = s0[4 * q2 + 3];
      float y0 = s1[4 * q2 + 0], y1 = s1[4 * q2 + 1], y2 = s1[4 * q2 + 2], y3 = s1[4 * q2 + 3];
      asm("v_cvt_pk_bf16_f32 %0, %1, %2" : "=v"(pk[0][q2][0]) : "v"(x0), "v"(x1));
      asm("v_cvt_pk_bf16_f32 %0, %1, %2" : "=v"(pk[0][q2][1]) : "v"(x2), "v"(x3));
      asm("v_cvt_pk_bf16_f32 %0, %1, %2" : "=v"(pk[1][q2][0]) : "v"(y0), "v"(y1));
      asm("v_cvt_pk_bf16_f32 %0, %1, %2" : "=v"(pk[1][q2][1]) : "v"(y2), "v"(y3));
    }
#pragma unroll
    for (int kvb = 0; kvb < 2; ++kvb) {
      asm volatile("v_permlane32_swap_b32 %0, %1" : "+v"(pk[kvb][0][0]), "+v"(pk[kvb][1][0]));
      asm volatile("v_permlane32_swap_b32 %0, %1" : "+v"(pk[kvb][0][1]), "+v"(pk[kvb][1][1]));
      asm volatile("v_permlane32_swap_b32 %0, %1" : "+v"(pk[kvb][2][0]), "+v"(pk[kvb][3][0]));
      asm volatile("v_permlane32_swap_b32 %0, %1" : "+v"(pk[kvb][2][1]), "+v"(pk[kvb][3][1]));
    }

    // PV: O^T[d][q] += V^T[d][kv] . P[kv][q]; ks covers kv 16-block
#pragma unroll
    for (int ks = 0; ks < 4; ++ks) {
      const int kvb = ks >> 1, kshi = ks & 1;
      uint4 pu;
      pu.x = pk[kvb][2 * kshi][0];
      pu.y = pk[kvb][2 * kshi][1];
      pu.z = pk[kvb][2 * kshi + 1][0];
      pu.w = pk[kvb][2 * kshi + 1][1];
      bf16x8 pf = __builtin_bit_cast(bf16x8, pu);
      bf16x8 v0 = __builtin_bit_cast(bf16x8, *(const uint4*)(Vc + voffa[ks]));
      bf16x8 v1 = __builtin_bit_cast(bf16x8, *(const uint4*)(Vc + voffb[ks]));
      __builtin_amdgcn_s_setprio(1);
      O0 = __builtin_amdgcn_mfma_f32_32x32x16_bf16(v0, pf, O0, 0, 0, 0);
      O1 = __builtin_amdgcn_mfma_f32_32x32x16_bf16(v1, pf, O1, 0, 0, 0);
      __builtin_amdgcn_s_setprio(0);
    }
  };

  const int ktb = c * 4;
  const int kte = min(ktb + 4, qt + 1);
  for (int kt0 = ktb; kt0 < kte; kt0 += 2) {
    const bool two = (kt0 + 1 < kte);  // block-uniform
    __syncthreads();                   // previous round's LDS reads done
    ATTN_STAGE(kt0, Ks[0], Vs[0]);
    if (two) ATTN_STAGE(kt0 + 1, Ks[1], Vs[1]);
    __syncthreads();                   // drains vmcnt -> both tiles staged
    do_tile(kt0, Ks[0], Vs[0]);
    if (two) do_tile(kt0 + 1, Ks[1], Vs[1]);
  }

  // write partials: pML fp32, pO fp16. O^T: d = dblk*32 + (rg&3) + 4g1 + 8(rg>>2), q = ql.
  const int qrow = qh * 32 + ql;
  float* pml = pML + (size_t)pid * 256 + sub * 128;
  if (g1 == 0) {
    pml[qrow] = mm;
    pml[64 + qrow] = lsum;
  }
  ushort* po = pOh + ((size_t)(pid * 2 + sub) * 64 + qrow) * 64;
#pragma unroll
  for (int q2 = 0; q2 < 4; ++q2) {
    uint2 u0, u1;
    u0.x = (unsigned)f2h(O0[4 * q2 + 0]) | ((unsigned)f2h(O0[4 * q2 + 1]) << 16);
    u0.y = (unsigned)f2h(O0[4 * q2 + 2]) | ((unsigned)f2h(O0[4 * q2 + 3]) << 16);
    u1.x = (unsigned)f2h(O1[4 * q2 + 0]) | ((unsigned)f2h(O1[4 * q2 + 1]) << 16);
    u1.y = (unsigned)f2h(O1[4 * q2 + 2]) | ((unsigned)f2h(O1[4 * q2 + 3]) << 16);
    *(uint2*)(po + q2 * 8 + g1 * 4) = u0;
    *(uint2*)(po + 32 + q2 * 8 + g1 * 4) = u1;
  }
}

// ---------------- combine partials + diff + RMSNorm ----------------
// block = (qt, h), 256 threads: thread t -> row = t>>2, quad = t&3 (16 ch each)
__global__ __launch_bounds__(256) void combine_kernel(
    const ushort* __restrict__ pOh, const float* __restrict__ pML,
    const float* __restrict__ lq1, const float* __restrict__ lk1,
    const float* __restrict__ lq2, const float* __restrict__ lk2,
    const float* __restrict__ gamma, ushort* __restrict__ attn_out) {
  const int qt = blockIdx.x, h = blockIdx.y;
  const int nc = (qt >> 2) + 1;
  const int pbase = h * 144 + qoff4(qt);
  const int t = threadIdx.x, row = t >> 2, quad = t & 3;
  const int lane = t & 63;

  // lambda = exp(lq1.lk1) - exp(lq2.lk2) + LAM_INIT
  float lam;
  {
    int d = lane & 31;
    float a1 = lq1[d] * lk1[d];
    float a2 = lq2[d] * lk2[d];
#pragma unroll
    for (int m = 16; m >= 1; m >>= 1) {
      a1 += __shfl_xor(a1, m);
      a2 += __shfl_xor(a2, m);
    }
    lam = expf(a1) - expf(a2) + LAM_INIT;
  }

  float M[2] = {-1e30f, -1e30f};
  for (int c = 0; c < nc; ++c) {
    const float* ml = pML + (size_t)(pbase + c) * 256;
    M[0] = fmaxf(M[0], ml[row]);
    M[1] = fmaxf(M[1], ml[128 + row]);
  }
  float L[2] = {0.f, 0.f};
  float acc[2][16];
#pragma unroll
  for (int s = 0; s < 2; ++s)
#pragma unroll
    for (int v = 0; v < 16; ++v) acc[s][v] = 0.f;

  for (int c = 0; c < nc; ++c) {
    const int pid = pbase + c;
    const float* ml = pML + (size_t)pid * 256;
#pragma unroll
    for (int s = 0; s < 2; ++s) {
      float mc = ml[s * 128 + row];
      float lc = ml[s * 128 + 64 + row];
      float wgt = exp2f((mc - M[s]) * C1EXP);  // raw-S units
      L[s] += lc * wgt;
      const ushort* op = pOh + ((size_t)(pid * 2 + s) * 64 + row) * 64 + quad * 16;
      uint4 ua = *(const uint4*)op;
      uint4 ub = *(const uint4*)(op + 8);
      unsigned uu[8] = {ua.x, ua.y, ua.z, ua.w, ub.x, ub.y, ub.z, ub.w};
#pragma unroll
      for (int j = 0; j < 8; ++j) {
        acc[s][2 * j + 0] += h2f((ushort)(uu[j] & 0xffffu)) * wgt;
        acc[s][2 * j + 1] += h2f((ushort)(uu[j] >> 16)) * wgt;
      }
    }
  }

  float inv0 = 1.f / L[0], inv1 = 1.f / L[1];
  float wv[16], ss = 0.f;
#pragma unroll
  for (int j = 0; j < 16; ++j) {
    float val = acc[0][j] * inv0 - lam * (acc[1][j] * inv1);
    wv[j] = val;
    ss += val * val;
  }
  ss += __shfl_xor(ss, 1);
  ss += __shfl_xor(ss, 2);
  float scl = rsqrtf(ss * (1.f / 64.f) + 1e-5f) * ONE_M_LI;

  union { ushort hs[16]; uint4 u[2]; } outp;
#pragma unroll
  for (int j = 0; j < 16; ++j)
    outp.hs[j] = f2b(wv[j] * scl * gamma[quad * 16 + j]);
  uint4* dst = (uint4*)(attn_out + (size_t)(qt * 64 + row) * 1024 + h * 64 + quad * 16);
  dst[0] = outp.u[0];
  dst[1] = outp.u[1];
}

extern "C" void kernel_launch(void* const* d_in, const int* in_sizes, int n_in,
                              void* d_out, int out_size, void* d_ws, size_t ws_size,
                              hipStream_t stream) {
  const float* x = (const float*)d_in[0];
  const float* Wq = (const float*)d_in[1];
  const float* Wk = (const float*)d_in[2];
  const float* Wv = (const float*)d_in[3];
  const float* Wo = (const float*)d_in[4];
  const float* lq1 = (const float*)d_in[5];
  const float* lk1 = (const float*)d_in[6];
  const float* lq2 = (const float*)d_in[7];
  const float* lk2 = (const float*)d_in[8];
  const float* gamma = (const float*)d_in[9];
  (void)in_sizes; (void)n_in; (void)out_size; (void)ws_size;

  char* ws = (char*)d_ws;
  ushort* xb = (ushort*)(ws);
  ushort* w1 = (ushort*)(ws + (4ull << 20));
  ushort* wob = (ushort*)(ws + (10ull << 20));
  ushort* qkv = (ushort*)(ws + (12ull << 20));
  ushort* vt = (ushort*)(ws + (24ull << 20));
  ushort* atn = (ushort*)(ws + (28ull << 20));
  float* cosT = (float*)(ws + (32ull << 20));
  float* sinT = (float*)(ws + (32ull << 20) + 2048 * 16 * 4);
  const size_t pO_off = (33ull << 20);
  const size_t pml_off = pO_off + 2304ull * 2 * 64 * 64 * 2;  // fp16 partials
  ushort* pOh = (ushort*)(ws + pO_off);
  float* pML = (float*)(ws + pml_off);

  prep_kernel<<<3200, 256, 0, stream>>>(x, Wq, Wk, Wv, Wo, xb, w1, wob, cosT, sinT);
  gemm_bt<64, 128, 1><<<dim3(24, 32), 256, 0, stream>>>(xb, w1, (void*)qkv, 2048, 3072, 1024, 1, cosT, sinT, vt);
  attn_split_kernel<<<2304, 256, 0, stream>>>(qkv, vt, pOh, pML);
  combine_kernel<<<dim3(32, 16), 256, 0, stream>>>(pOh, pML, lq1, lk1, lq2, lk2, gamma, atn);
  gemm_bt<64, 64, 0><<<dim3(16, 32), 256, 0, stream>>>(atn, wob, d_out, 2048, 1024, 1024, 0, nullptr, nullptr, nullptr);
}